// Round 2
// baseline (301.458 us; speedup 1.0000x reference)
//
#include <hip/hip_runtime.h>
#include <hip/hip_bf16.h>

#define B_ 16
#define N_ 1024
#define F_ 256
#define ALPHA 0.2f
#define NEG_BIG -9.0e15f

typedef float f4 __attribute__((ext_vector_type(4)));

// ---------------------------------------------------------------------------
// K1: Wh = h @ W   (M = B*N = 16384, K = 256, N = 256), fp32 tiled GEMM
// 64x64 tile per block, 4x4 micro-tile per thread, LDS staged (pad 68 keeps
// float4 16B alignment and breaks power-of-2 bank strides).
// ---------------------------------------------------------------------------
__global__ __launch_bounds__(256) void k_gemm_hw(const float* __restrict__ h,
                                                 const float* __restrict__ W,
                                                 float* __restrict__ Wh) {
    __shared__ float sA[64][68];
    __shared__ float sB[64][68];
    const int t = threadIdx.x;
    const int tx = t & 15, ty = t >> 4;
    const int m0 = blockIdx.y * 64, n0 = blockIdx.x * 64;
    const int row0 = ty * 4, col0 = tx * 4;
    float acc[4][4] = {};

    for (int kt = 0; kt < 4; ++kt) {
        const int k0 = kt * 64;
#pragma unroll
        for (int rep = 0; rep < 4; ++rep) {
            const int idx = rep * 256 + t;
            const int r = idx >> 4, c4 = idx & 15;
            *(f4*)&sA[r][c4 * 4] =
                *(const f4*)(h + (size_t)(m0 + r) * F_ + k0 + c4 * 4);
            *(f4*)&sB[r][c4 * 4] =
                *(const f4*)(W + (size_t)(k0 + r) * F_ + n0 + c4 * 4);
        }
        __syncthreads();
#pragma unroll 4
        for (int kk = 0; kk < 64; kk += 4) {
            f4 av[4], bv[4];
#pragma unroll
            for (int i = 0; i < 4; ++i) av[i] = *(const f4*)&sA[row0 + i][kk];
#pragma unroll
            for (int q = 0; q < 4; ++q) bv[q] = *(const f4*)&sB[kk + q][col0];
#pragma unroll
            for (int i = 0; i < 4; ++i)
#pragma unroll
                for (int q = 0; q < 4; ++q)
#pragma unroll
                    for (int j = 0; j < 4; ++j)
                        acc[i][j] += av[i][q] * bv[q][j];
        }
        __syncthreads();
    }

#pragma unroll
    for (int i = 0; i < 4; ++i) {
        f4 o;
#pragma unroll
        for (int j = 0; j < 4; ++j) o[j] = acc[i][j];
        *(f4*)(Wh + (size_t)(m0 + row0 + i) * F_ + n0 + col0) = o;
    }
}

// ---------------------------------------------------------------------------
// K2: e_i[row] = dot(Wh[row,:], a1), e_j[row] = dot(Wh[row,:], a2)
// One wave per row, shuffle reduce.
// ---------------------------------------------------------------------------
__global__ __launch_bounds__(256) void k_e(const float* __restrict__ Wh,
                                           const float* __restrict__ a,
                                           float* __restrict__ ei,
                                           float* __restrict__ ej) {
    const int lane = threadIdx.x & 63;
    const int row = blockIdx.x * 4 + (threadIdx.x >> 6);
    const f4 wv = *(const f4*)(Wh + (size_t)row * F_ + lane * 4);
    const f4 a1 = *(const f4*)(a + lane * 4);
    const f4 a2 = *(const f4*)(a + F_ + lane * 4);
    float s1 = wv[0] * a1[0] + wv[1] * a1[1] + wv[2] * a1[2] + wv[3] * a1[3];
    float s2 = wv[0] * a2[0] + wv[1] * a2[1] + wv[2] * a2[2] + wv[3] * a2[3];
#pragma unroll
    for (int off = 32; off > 0; off >>= 1) {
        s1 += __shfl_down(s1, off);
        s2 += __shfl_down(s2, off);
    }
    if (lane == 0) {
        ei[row] = s1;
        ej[row] = s2;
    }
}

// ---------------------------------------------------------------------------
// K3: fused leaky + mask + online-softmax + att@Wh + ELU.
// One block per (b, 32-row i-tile). j-loop over 32-wide tiles:
//   stage Wh[b, j0:j0+32, :] in LDS, compute 32x32 scores, online softmax
//   (m,l init NEG_BIG/0 reproduces reference all-masked semantics exactly),
//   fp32 FMA accumulate 8 rows x 4 cols per thread.
// XCD swizzle: each XCD (id%8) owns all 32 i-tiles of 2 batches so Wh[b]
// (1 MB) stays resident in that XCD's 4 MB L2.
// ---------------------------------------------------------------------------
__global__ __launch_bounds__(256) void k_attn(const float* __restrict__ Wh,
                                              const float* __restrict__ ei,
                                              const float* __restrict__ ej,
                                              const int* __restrict__ adj,
                                              float* __restrict__ out) {
    const int id = blockIdx.x;
    const int xcd = id & 7, slot = id >> 3;
    const int b = xcd * 2 + (slot >> 5);
    const int it = slot & 31;
    const int i0 = it * 32;

    __shared__ float sWh[32][256];
    __shared__ float sP[32][36];  // pad 36: 16B-aligned rows, 4-way worst bank
    __shared__ float sEi[32], sEj[32], sM[32], sL[32], sF[32];

    const int t = threadIdx.x;
    const int tc = t & 63, tr = t >> 6;
    const int rbase = tr * 8;

    float acc[8][4] = {};

    if (t < 32) {
        sEi[t] = ei[b * N_ + i0 + t];
        sM[t] = NEG_BIG;
        sL[t] = 0.f;
    }
    __syncthreads();

    for (int jt = 0; jt < 32; ++jt) {
        const int j0 = jt * 32;
        // stage Wh j-tile (32x256 f32 = 32 KB), coalesced float4
#pragma unroll
        for (int rep = 0; rep < 8; ++rep) {
            const int idx = rep * 256 + t;
            const int jr = idx >> 6, c4 = idx & 63;
            *(f4*)&sWh[jr][c4 * 4] =
                *(const f4*)(Wh + (size_t)(b * N_ + j0 + jr) * F_ + c4 * 4);
        }
        if (t < 32) sEj[t] = ej[b * N_ + j0 + t];
        __syncthreads();

        // scores: leaky(e_i + e_j), masked by adj
        {
            const int j = t & 31, ig = t >> 5;
            const float evj = sEj[j];
#pragma unroll
            for (int k = 0; k < 4; ++k) {
                const int i = ig + k * 8;
                float s = sEi[i] + evj;
                s = s > 0.f ? s : ALPHA * s;
                const int ad = adj[(size_t)(b * N_ + i0 + i) * N_ + j0 + j];
                sP[i][j] = ad > 0 ? s : NEG_BIG;
            }
        }
        __syncthreads();

        // online softmax state update (one thread per row)
        if (t < 32) {
            const int r = t;
            const float mo = sM[r];
            float tm = sP[r][0];
#pragma unroll
            for (int j = 1; j < 32; ++j) tm = fmaxf(tm, sP[r][j]);
            const float mn = fmaxf(mo, tm);
            const float fac = __expf(mo - mn);
            float sum = 0.f;
#pragma unroll
            for (int j = 0; j < 32; ++j) {
                const float p = __expf(sP[r][j] - mn);
                sum += p;
                sP[r][j] = p;
            }
            sL[r] = sL[r] * fac + sum;
            sM[r] = mn;
            sF[r] = fac;
        }
        __syncthreads();

        // PV: acc = acc*fac + P(32x32) @ Wh_tile(32x256)
        {
            float fr[8];
#pragma unroll
            for (int r = 0; r < 8; ++r) fr[r] = sF[rbase + r];
#pragma unroll
            for (int r = 0; r < 8; ++r)
#pragma unroll
                for (int c = 0; c < 4; ++c) acc[r][c] *= fr[r];
#pragma unroll
            for (int jg = 0; jg < 8; ++jg) {
                f4 wh[4];
#pragma unroll
                for (int q = 0; q < 4; ++q)
                    wh[q] = *(const f4*)&sWh[jg * 4 + q][tc * 4];
#pragma unroll
                for (int r = 0; r < 8; ++r) {
                    const f4 p4 = *(const f4*)&sP[rbase + r][jg * 4];
#pragma unroll
                    for (int q = 0; q < 4; ++q)
#pragma unroll
                        for (int c = 0; c < 4; ++c)
                            acc[r][c] += p4[q] * wh[q][c];
                }
            }
        }
        __syncthreads();
    }

    // epilogue: normalize, ELU, store
#pragma unroll
    for (int r = 0; r < 8; ++r) {
        const float inv = 1.f / sL[rbase + r];
        f4 o;
#pragma unroll
        for (int c = 0; c < 4; ++c) {
            const float v = acc[r][c] * inv;
            o[c] = v > 0.f ? v : expm1f(v);
        }
        *(f4*)(out + (size_t)(b * N_ + i0 + rbase + r) * F_ + tc * 4) = o;
    }
}

// ---------------------------------------------------------------------------
extern "C" void kernel_launch(void* const* d_in, const int* in_sizes, int n_in,
                              void* d_out, int out_size, void* d_ws, size_t ws_size,
                              hipStream_t stream) {
    const float* h = (const float*)d_in[0];
    const int* adj = (const int*)d_in[1];
    const float* W = (const float*)d_in[2];
    const float* a = (const float*)d_in[3];
    float* out = (float*)d_out;

    float* Wh = (float*)d_ws;                 // 16384*256 f32 = 16 MB
    float* ei = Wh + (size_t)B_ * N_ * F_;    // 16384 f32
    float* ej = ei + (size_t)B_ * N_;         // 16384 f32

    k_gemm_hw<<<dim3(4, 256), 256, 0, stream>>>(h, W, Wh);
    k_e<<<(B_ * N_) / 4, 256, 0, stream>>>(Wh, a, ei, ej);
    k_attn<<<512, 256, 0, stream>>>(Wh, ei, ej, adj, out);
}

// Round 3
// 200.302 us; speedup vs baseline: 1.5050x; 1.5050x over previous
//
#include <hip/hip_runtime.h>

#define B_ 16
#define N_ 1024
#define F_ 256
#define ALPHA 0.2f
#define NEG_BIG -9.0e15f

typedef float f4 __attribute__((ext_vector_type(4)));
typedef float f32x4 __attribute__((ext_vector_type(4)));
typedef short s16x8 __attribute__((ext_vector_type(8)));
typedef short s16x4 __attribute__((ext_vector_type(4)));

__device__ inline unsigned short f2b(float x) {  // f32 -> bf16 RNE
    unsigned int u = __float_as_uint(x);
    u = (u + 0x7FFFu + ((u >> 16) & 1u)) >> 16;
    return (unsigned short)u;
}
__device__ inline float b2f(unsigned short s) {
    unsigned int u = ((unsigned int)s) << 16;
    return __uint_as_float(u);
}

// ---------------------------------------------------------------------------
// K0: wa1[k] = sum_f W[k][f]*a1[f]; wa2 likewise. (e_i = h@wa1 == (h@W)@a1)
// 1 block, 4 waves; wave processes 64 rows serially, lanes cover f (coalesced).
// ---------------------------------------------------------------------------
__global__ __launch_bounds__(256) void k_wa(const float* __restrict__ W,
                                            const float* __restrict__ a,
                                            float* __restrict__ wa) {
    __shared__ float sa[512];
    const int t = threadIdx.x, lane = t & 63, w = t >> 6;
    sa[t] = a[t];
    sa[t + 256] = a[t + 256];
    __syncthreads();
    const f4 a1 = *(const f4*)(sa + lane * 4);
    const f4 a2 = *(const f4*)(sa + 256 + lane * 4);
    for (int r = 0; r < 64; ++r) {
        const int row = w * 64 + r;
        const f4 wv = *(const f4*)(W + (size_t)row * F_ + lane * 4);
        float s1 = wv[0]*a1[0] + wv[1]*a1[1] + wv[2]*a1[2] + wv[3]*a1[3];
        float s2 = wv[0]*a2[0] + wv[1]*a2[1] + wv[2]*a2[2] + wv[3]*a2[3];
#pragma unroll
        for (int off = 32; off > 0; off >>= 1) {
            s1 += __shfl_xor(s1, off);
            s2 += __shfl_xor(s2, off);
        }
        if (lane == 0) { wa[row] = s1; wa[256 + row] = s2; }
    }
}

// ---------------------------------------------------------------------------
// K1: WhT[b][f][m] (bf16) = transpose(h @ W).  MFMA 16x16x32 bf16.
// Block: 64m x 64f, 4 waves (wave = 16m x 64f). LDS: A[m][k], WT[f][k] bf16,
// rows 128B, XOR chunk swizzle ((row&7)<<4) -> 2-way-free frag reads (G4).
// C layout (m89): col=lane&15 (f), row=(lane>>4)*4+q (m) -> 4 consecutive m
// per lane pack to one 8B store into WhT.
// ---------------------------------------------------------------------------
__global__ __launch_bounds__(256) void k_gemm(const float* __restrict__ h,
                                              const float* __restrict__ W,
                                              unsigned short* __restrict__ WhT) {
    __shared__ unsigned short sA[64 * 64];  // [m][k] swizzled
    __shared__ unsigned short sB[64 * 64];  // [f][k] swizzled (W^T)
    const int t = threadIdx.x, l = t & 63, w = t >> 6;
    const int m0 = blockIdx.x * 64, f0 = blockIdx.y * 64;
    const int jg = l >> 4, li = l & 15;
    f32x4 acc[4] = {};

    for (int kt = 0; kt < 4; ++kt) {
        const int k0 = kt * 64;
        if (kt) __syncthreads();
        // stage A: 512 chunks of 8 bf16; thread t handles chunks 2t, 2t+1
#pragma unroll
        for (int r = 0; r < 2; ++r) {
            const int c = t * 2 + r;
            const int m = c >> 3, kc = c & 7;
            const f4 lo = *(const f4*)(h + (size_t)(m0 + m) * F_ + k0 + kc * 8);
            const f4 hi = *(const f4*)(h + (size_t)(m0 + m) * F_ + k0 + kc * 8 + 4);
            s16x8 v;
            v[0]=(short)f2b(lo[0]); v[1]=(short)f2b(lo[1]); v[2]=(short)f2b(lo[2]); v[3]=(short)f2b(lo[3]);
            v[4]=(short)f2b(hi[0]); v[5]=(short)f2b(hi[1]); v[6]=(short)f2b(hi[2]); v[7]=(short)f2b(hi[3]);
            *(s16x8*)((char*)sA + m * 128 + ((kc ^ (m & 7)) << 4)) = v;
        }
        // stage B = W^T: thread t: k rows kr..kr+3, f cols fc..fc+3
        {
            const int kr = (t >> 4) * 4, fc = (t & 15) * 4;
            f4 r0 = *(const f4*)(W + (size_t)(k0 + kr + 0) * F_ + f0 + fc);
            f4 r1 = *(const f4*)(W + (size_t)(k0 + kr + 1) * F_ + f0 + fc);
            f4 r2 = *(const f4*)(W + (size_t)(k0 + kr + 2) * F_ + f0 + fc);
            f4 r3 = *(const f4*)(W + (size_t)(k0 + kr + 3) * F_ + f0 + fc);
#pragma unroll
            for (int ff = 0; ff < 4; ++ff) {
                const int f = fc + ff;
                s16x4 v;
                v[0]=(short)f2b(r0[ff]); v[1]=(short)f2b(r1[ff]);
                v[2]=(short)f2b(r2[ff]); v[3]=(short)f2b(r3[ff]);
                *(s16x4*)((char*)sB + f * 128 + (((kr >> 3) ^ (f & 7)) << 4) + (kr & 7) * 2) = v;
            }
        }
        __syncthreads();
        // compute: wave -> 16 m rows, 4 f-tiles
        const int mloc = w * 16 + li;
#pragma unroll
        for (int ks = 0; ks < 2; ++ks) {
            const int kchunk = ks * 4 + jg;
            const s16x8 av = *(const s16x8*)((const char*)sA + mloc * 128 + ((kchunk ^ (mloc & 7)) << 4));
#pragma unroll
            for (int ft = 0; ft < 4; ++ft) {
                const int f = ft * 16 + li;
                const s16x8 bv = *(const s16x8*)((const char*)sB + f * 128 + ((kchunk ^ (f & 7)) << 4));
                acc[ft] = __builtin_amdgcn_mfma_f32_16x16x32_bf16(av, bv, acc[ft], 0, 0, 0);
            }
        }
    }
    // epilogue: WhT[b][f][m], lane holds 4 consecutive m at fixed f
    const int bb = m0 >> 10;
    const int mb = (m0 & 1023) + w * 16 + jg * 4;
#pragma unroll
    for (int ft = 0; ft < 4; ++ft) {
        const int fg = f0 + ft * 16 + li;
        s16x4 v;
        v[0]=(short)f2b(acc[ft][0]); v[1]=(short)f2b(acc[ft][1]);
        v[2]=(short)f2b(acc[ft][2]); v[3]=(short)f2b(acc[ft][3]);
        *(s16x4*)(WhT + ((size_t)(bb * 256 + fg)) * 1024 + mb) = v;
    }
}

// ---------------------------------------------------------------------------
// K2': ei = h@wa1, ej = h@wa2 (fp32 exact). One wave per row.
// ---------------------------------------------------------------------------
__global__ __launch_bounds__(256) void k_e2(const float* __restrict__ h,
                                            const float* __restrict__ wa,
                                            float* __restrict__ ei,
                                            float* __restrict__ ej) {
    const int lane = threadIdx.x & 63;
    const int row = blockIdx.x * 4 + (threadIdx.x >> 6);
    const f4 hv = *(const f4*)(h + (size_t)row * F_ + lane * 4);
    const f4 w1 = *(const f4*)(wa + lane * 4);
    const f4 w2 = *(const f4*)(wa + 256 + lane * 4);
    float s1 = hv[0]*w1[0] + hv[1]*w1[1] + hv[2]*w1[2] + hv[3]*w1[3];
    float s2 = hv[0]*w2[0] + hv[1]*w2[1] + hv[2]*w2[2] + hv[3]*w2[3];
#pragma unroll
    for (int off = 32; off > 0; off >>= 1) {
        s1 += __shfl_xor(s1, off);
        s2 += __shfl_xor(s2, off);
    }
    if (lane == 0) { ei[row] = s1; ej[row] = s2; }
}

// ---------------------------------------------------------------------------
// K3: fused mask+leaky+online-softmax+PV(MFMA)+ELU.
// Block: 32 i-rows; 4 waves = (i-half) x (f-half 128). Wave's P A-fragment is
// computed in registers in native MFMA layout (row=l&15, k=(l>>4)*8+e).
// Wh B-operand staged via global_load_lds with pre-swizzled SOURCE (m173) into
// linear LDS; reads apply the same XOR -> conflict-free ds_read_b128.
// Defer-max (T13, THR=8); m init NEG_BIG reproduces all-masked => uniform.
// ---------------------------------------------------------------------------
__global__ __launch_bounds__(256) void k_attn(const unsigned short* __restrict__ WhT,
                                              const float* __restrict__ ei_g,
                                              const float* __restrict__ ej_g,
                                              const int* __restrict__ adj,
                                              float* __restrict__ out) {
    const int id = blockIdx.x;
    const int xcd = id & 7, slot = id >> 3;           // L2 locality: 2 batches/XCD
    const int b = xcd * 2 + (slot >> 5);
    const int i0 = (slot & 31) * 32;

    __shared__ unsigned short sT[2 * 16384];          // 2 x [256f][64j] bf16, 64 KB

    const int t = threadIdx.x, l = t & 63, w = t >> 6;
    const int ih = w >> 1, fbase = (w & 1) * 128;
    const int li = l & 15, jg = l >> 4;
    const int irow = i0 + ih * 16 + li;

    const unsigned short* whb = WhT + (size_t)b * 256 * 1024;
    const int* adjrow = adj + ((size_t)b * N_ + irow) * N_;
    const float* ejb = ej_g + b * N_;
    const float eival = ei_g[b * N_ + irow];

    float m = NEG_BIG, ll = 0.f;
    f32x4 acc[8] = {};

    // ---- staging: pre-swizzled source, linear LDS dest (rule 21 / m173) ----
    auto stage = [&](int j0, int buf) {
#pragma unroll
        for (int r = 0; r < 8; ++r) {
            const int c0 = (w * 8 + r) * 64;          // wave-uniform chunk base
            const int c = c0 + l;
            const int f_o = c >> 3, jc_o = c & 7;
            const int jc_s = jc_o ^ (f_o & 7);
            const unsigned short* g = whb + (size_t)f_o * 1024 + j0 + jc_s * 8;
            __builtin_amdgcn_global_load_lds(
                (const __attribute__((address_space(1))) unsigned int*)g,
                (__attribute__((address_space(3))) unsigned int*)((char*)sT + buf * 32768 + c0 * 16),
                16, 0, 0);
        }
    };

    stage(0, 0);
    int4 adjc[4];
#pragma unroll
    for (int q = 0; q < 4; ++q)
        adjc[q] = *(const int4*)(adjrow + (q >> 1) * 32 + jg * 8 + (q & 1) * 4);
    __syncthreads();

    for (int s = 0; s < 16; ++s) {
        const int cur = s & 1;
        int4 adjn[4];
        if (s < 15) {
            const int j0n = (s + 1) * 64;
#pragma unroll
            for (int q = 0; q < 4; ++q)
                adjn[q] = *(const int4*)(adjrow + j0n + (q >> 1) * 32 + jg * 8 + (q & 1) * 4);
        }
#pragma unroll
        for (int sub = 0; sub < 2; ++sub) {
            const int jbase = s * 64 + sub * 32 + jg * 8;
            const f4 ej0 = *(const f4*)(ejb + jbase);
            const f4 ej1 = *(const f4*)(ejb + jbase + 4);
            const int4 a0 = adjc[sub * 2], a1 = adjc[sub * 2 + 1];
            float p[8];
            float tm = NEG_BIG;
#pragma unroll
            for (int e = 0; e < 8; ++e) {
                const float ejv = (e < 4) ? ej0[e] : ej1[e - 4];
                float sc = eival + ejv;
                sc = sc > 0.f ? sc : ALPHA * sc;
                const int ad = (e < 4) ? ((const int*)&a0)[e] : ((const int*)&a1)[e - 4];
                sc = ad > 0 ? sc : NEG_BIG;
                p[e] = sc;
                tm = fmaxf(tm, sc);
            }
            tm = fmaxf(tm, __shfl_xor(tm, 16));
            tm = fmaxf(tm, __shfl_xor(tm, 32));
            if (__any(tm > m + 8.f)) {                // defer-max rescale
                const float mn = fmaxf(m, tm);
                const float fac = __expf(m - mn);
                m = mn;
                ll *= fac;
                float fr[4];
#pragma unroll
                for (int q = 0; q < 4; ++q) fr[q] = __shfl(fac, jg * 4 + q);
#pragma unroll
                for (int ft = 0; ft < 8; ++ft)
#pragma unroll
                    for (int q = 0; q < 4; ++q) acc[ft][q] *= fr[q];
            }
            float sum = 0.f;
            s16x8 afrag;
#pragma unroll
            for (int e = 0; e < 8; ++e) {
                const float pe = __expf(p[e] - m);
                const unsigned short pb = f2b(pe);
                afrag[e] = (short)pb;
                sum += b2f(pb);                       // sum the rounded P (consistency)
            }
            sum += __shfl_xor(sum, 16);
            sum += __shfl_xor(sum, 32);
            ll += sum;
#pragma unroll
            for (int ft = 0; ft < 8; ++ft) {
                const int f = fbase + ft * 16 + li;
                const int jcr = sub * 4 + jg;
                const s16x8 bv = *(const s16x8*)((const char*)sT + cur * 32768 + f * 128 + ((jcr ^ (f & 7)) << 4));
                acc[ft] = __builtin_amdgcn_mfma_f32_16x16x32_bf16(afrag, bv, acc[ft], 0, 0, 0);
            }
        }
        if (s < 15) {
            stage((s + 1) * 64, cur ^ 1);
#pragma unroll
            for (int q = 0; q < 4; ++q) adjc[q] = adjn[q];
        }
        __syncthreads();
    }

    // epilogue: normalize, ELU, store (C rows = jg*4+q, cols = li per f-tile)
    const float il = 1.f / ll;
    float inv[4];
#pragma unroll
    for (int q = 0; q < 4; ++q) inv[q] = __shfl(il, jg * 4 + q);
#pragma unroll
    for (int ft = 0; ft < 8; ++ft) {
#pragma unroll
        for (int q = 0; q < 4; ++q) {
            float v = acc[ft][q] * inv[q];
            v = v > 0.f ? v : __expf(v) - 1.f;
            out[((size_t)b * N_ + i0 + ih * 16 + jg * 4 + q) * F_ + fbase + ft * 16 + li] = v;
        }
    }
}

// ---------------------------------------------------------------------------
extern "C" void kernel_launch(void* const* d_in, const int* in_sizes, int n_in,
                              void* d_out, int out_size, void* d_ws, size_t ws_size,
                              hipStream_t stream) {
    const float* h = (const float*)d_in[0];
    const int* adj = (const int*)d_in[1];
    const float* W = (const float*)d_in[2];
    const float* a = (const float*)d_in[3];
    float* out = (float*)d_out;

    unsigned short* WhT = (unsigned short*)d_ws;          // 8 MB bf16 [b][f][m]
    float* wa = (float*)(WhT + (size_t)B_ * N_ * F_);     // 512
    float* ei = wa + 512;                                 // 16384
    float* ej = ei + (size_t)B_ * N_;                     // 16384

    k_wa<<<1, 256, 0, stream>>>(W, a, wa);
    k_gemm<<<dim3(256, 4), 256, 0, stream>>>(h, W, WhT);
    k_e2<<<(B_ * N_) / 4, 256, 0, stream>>>(h, wa, ei, ej);
    k_attn<<<512, 256, 0, stream>>>(WhT, ei, ej, adj, out);
}

// Round 5
// 160.946 us; speedup vs baseline: 1.8730x; 1.2445x over previous
//
#include <hip/hip_runtime.h>
#include <hip/hip_bf16.h>

#define B_ 16
#define N_ 1024
#define F_ 256
#define ALPHA 0.2f
#define NEG_BIG -9.0e15f
#define LOG2E 1.4426950408889634f

typedef float f4 __attribute__((ext_vector_type(4)));
typedef float f32x4 __attribute__((ext_vector_type(4)));
typedef short s16x8 __attribute__((ext_vector_type(8)));
typedef short s16x4 __attribute__((ext_vector_type(4)));

__device__ inline short f2bs(float x) {  // f32 -> bf16 bits via HW cvt (RNE)
    __hip_bfloat16 h = __float2bfloat16(x);
    return __builtin_bit_cast(short, h);
}

// ---------------------------------------------------------------------------
// K0: wa1[k] = sum_f W[k][f]*a1[f]; wa2 likewise. 64 blocks, 1 row per wave.
// ---------------------------------------------------------------------------
__global__ __launch_bounds__(256) void k_wa(const float* __restrict__ W,
                                            const float* __restrict__ a,
                                            float* __restrict__ wa) {
    const int t = threadIdx.x, lane = t & 63, w = t >> 6;
    const int row = blockIdx.x * 4 + w;
    const f4 wv = *(const f4*)(W + (size_t)row * F_ + lane * 4);
    const f4 a1 = *(const f4*)(a + lane * 4);
    const f4 a2 = *(const f4*)(a + F_ + lane * 4);
    float s1 = wv[0]*a1[0] + wv[1]*a1[1] + wv[2]*a1[2] + wv[3]*a1[3];
    float s2 = wv[0]*a2[0] + wv[1]*a2[1] + wv[2]*a2[2] + wv[3]*a2[3];
#pragma unroll
    for (int off = 32; off > 0; off >>= 1) {
        s1 += __shfl_xor(s1, off);
        s2 += __shfl_xor(s2, off);
    }
    if (lane == 0) { wa[row] = s1; wa[256 + row] = s2; }
}

// ---------------------------------------------------------------------------
// K1: WhT[b][f][m] (bf16) = transpose(h @ W).  MFMA 16x16x32 bf16.
// 64m x 64f block, 4 waves. XOR chunk swizzle on LDS rows (128 B).
// ---------------------------------------------------------------------------
__global__ __launch_bounds__(256) void k_gemm(const float* __restrict__ h,
                                              const float* __restrict__ W,
                                              unsigned short* __restrict__ WhT) {
    __shared__ unsigned short sA[64 * 64];  // [m][k] swizzled
    __shared__ unsigned short sB[64 * 64];  // [f][k] swizzled (W^T)
    const int t = threadIdx.x, l = t & 63, w = t >> 6;
    const int m0 = blockIdx.x * 64, f0 = blockIdx.y * 64;
    const int jg = l >> 4, li = l & 15;
    f32x4 acc[4] = {};

    for (int kt = 0; kt < 4; ++kt) {
        const int k0 = kt * 64;
        if (kt) __syncthreads();
#pragma unroll
        for (int r = 0; r < 2; ++r) {
            const int c = t * 2 + r;
            const int m = c >> 3, kc = c & 7;
            const f4 lo = *(const f4*)(h + (size_t)(m0 + m) * F_ + k0 + kc * 8);
            const f4 hi = *(const f4*)(h + (size_t)(m0 + m) * F_ + k0 + kc * 8 + 4);
            s16x8 v;
            v[0]=f2bs(lo[0]); v[1]=f2bs(lo[1]); v[2]=f2bs(lo[2]); v[3]=f2bs(lo[3]);
            v[4]=f2bs(hi[0]); v[5]=f2bs(hi[1]); v[6]=f2bs(hi[2]); v[7]=f2bs(hi[3]);
            *(s16x8*)((char*)sA + m * 128 + ((kc ^ (m & 7)) << 4)) = v;
        }
        {
            const int kr = (t >> 4) * 4, fc = (t & 15) * 4;
            f4 r0 = *(const f4*)(W + (size_t)(k0 + kr + 0) * F_ + f0 + fc);
            f4 r1 = *(const f4*)(W + (size_t)(k0 + kr + 1) * F_ + f0 + fc);
            f4 r2 = *(const f4*)(W + (size_t)(k0 + kr + 2) * F_ + f0 + fc);
            f4 r3 = *(const f4*)(W + (size_t)(k0 + kr + 3) * F_ + f0 + fc);
#pragma unroll
            for (int ff = 0; ff < 4; ++ff) {
                const int f = fc + ff;
                s16x4 v;
                v[0]=f2bs(r0[ff]); v[1]=f2bs(r1[ff]); v[2]=f2bs(r2[ff]); v[3]=f2bs(r3[ff]);
                *(s16x4*)((char*)sB + f * 128 + (((kr >> 3) ^ (f & 7)) << 4) + (kr & 7) * 2) = v;
            }
        }
        __syncthreads();
        const int mloc = w * 16 + li;
#pragma unroll
        for (int ks = 0; ks < 2; ++ks) {
            const int kchunk = ks * 4 + jg;
            const s16x8 av = *(const s16x8*)((const char*)sA + mloc * 128 + ((kchunk ^ (mloc & 7)) << 4));
#pragma unroll
            for (int ft = 0; ft < 4; ++ft) {
                const int f = ft * 16 + li;
                const s16x8 bv = *(const s16x8*)((const char*)sB + f * 128 + ((kchunk ^ (f & 7)) << 4));
                acc[ft] = __builtin_amdgcn_mfma_f32_16x16x32_bf16(av, bv, acc[ft], 0, 0, 0);
            }
        }
    }
    const int bb = m0 >> 10;
    const int mb = (m0 & 1023) + w * 16 + jg * 4;
#pragma unroll
    for (int ft = 0; ft < 4; ++ft) {
        const int fg = f0 + ft * 16 + li;
        s16x4 v;
        v[0]=f2bs(acc[ft][0]); v[1]=f2bs(acc[ft][1]);
        v[2]=f2bs(acc[ft][2]); v[3]=f2bs(acc[ft][3]);
        *(s16x4*)(WhT + ((size_t)(bb * 256 + fg)) * 1024 + mb) = v;
    }
}

// ---------------------------------------------------------------------------
// K2': ei = (h@wa1)*log2e, ej = (h@wa2)*log2e  (fp32; pre-scaled so softmax
// uses raw exp2 — leaky commutes with positive scale). One wave per row.
// ---------------------------------------------------------------------------
__global__ __launch_bounds__(256) void k_e2(const float* __restrict__ h,
                                            const float* __restrict__ wa,
                                            float* __restrict__ ei,
                                            float* __restrict__ ej) {
    const int lane = threadIdx.x & 63;
    const int row = blockIdx.x * 4 + (threadIdx.x >> 6);
    const f4 hv = *(const f4*)(h + (size_t)row * F_ + lane * 4);
    const f4 w1 = *(const f4*)(wa + lane * 4);
    const f4 w2 = *(const f4*)(wa + 256 + lane * 4);
    float s1 = hv[0]*w1[0] + hv[1]*w1[1] + hv[2]*w1[2] + hv[3]*w1[3];
    float s2 = hv[0]*w2[0] + hv[1]*w2[1] + hv[2]*w2[2] + hv[3]*w2[3];
#pragma unroll
    for (int off = 32; off > 0; off >>= 1) {
        s1 += __shfl_xor(s1, off);
        s2 += __shfl_xor(s2, off);
    }
    if (lane == 0) { ei[row] = s1 * LOG2E; ej[row] = s2 * LOG2E; }
}

// ---------------------------------------------------------------------------
// K3: fused mask+leaky+online-softmax+PV(MFMA)+ELU.
// Issue-early double-buffered staging (T3/T14): stage(s+1) + adj/ej reg
// prefetch at TOP of iteration, compute hides the latency, one barrier/stage.
// Scores pre-scaled by log2e -> exp2 directly; defer-max THR = 8*log2e.
// ---------------------------------------------------------------------------
__global__ __launch_bounds__(256) void k_attn(const unsigned short* __restrict__ WhT,
                                              const float* __restrict__ ei_g,
                                              const float* __restrict__ ej_g,
                                              const int* __restrict__ adj,
                                              float* __restrict__ out) {
    const int id = blockIdx.x;
    const int xcd = id & 7, slot = id >> 3;           // 2 batches per XCD
    const int b = xcd * 2 + (slot >> 5);
    const int i0 = (slot & 31) * 32;

    __shared__ unsigned short sT[2 * 16384];          // 2 x [256f][64j] bf16

    const int t = threadIdx.x, l = t & 63, w = t >> 6;
    const int ih = w >> 1, fbase = (w & 1) * 128;
    const int li = l & 15, jg = l >> 4;
    const int irow = i0 + ih * 16 + li;

    const unsigned short* whb = WhT + (size_t)b * F_ * N_;
    const int* adjrow = adj + ((size_t)b * N_ + irow) * N_;
    const float* ejb = ej_g + b * N_;
    const float eival = ei_g[b * N_ + irow];

    // hoisted per-lane staging addresses (pre-swizzled source, linear dest)
    const unsigned short* gsrc[8];
    int ldst[8];
#pragma unroll
    for (int r = 0; r < 8; ++r) {
        const int c0 = (w * 8 + r) * 64;
        const int c = c0 + l;
        const int f_o = c >> 3;
        const int jc_s = (c & 7) ^ (f_o & 7);
        gsrc[r] = whb + (size_t)f_o * N_ + jc_s * 8;
        ldst[r] = c0 * 16;
    }
    auto stage = [&](int j0, int buf) {
#pragma unroll
        for (int r = 0; r < 8; ++r) {
            __builtin_amdgcn_global_load_lds(
                (const __attribute__((address_space(1))) unsigned int*)(gsrc[r] + j0),
                (__attribute__((address_space(3))) unsigned int*)((char*)sT + buf * 32768 + ldst[r]),
                16, 0, 0);
        }
    };

    float m = NEG_BIG, ll = 0.f;
    f32x4 acc[8] = {};

    stage(0, 0);
    int4 adjc[4];
    f4 ejc[4];
#pragma unroll
    for (int q = 0; q < 4; ++q) {
        adjc[q] = *(const int4*)(adjrow + (q >> 1) * 32 + jg * 8 + (q & 1) * 4);
        ejc[q] = *(const f4*)(ejb + (q >> 1) * 32 + jg * 8 + (q & 1) * 4);
    }
    __syncthreads();

    for (int s = 0; s < 16; ++s) {
        const int cur = s & 1;
        int4 adjn[4];
        f4 ejn[4];
        if (s < 15) {
            stage((s + 1) * 64, cur ^ 1);             // issue EARLY, hide under compute
            const int j0n = (s + 1) * 64;
#pragma unroll
            for (int q = 0; q < 4; ++q) {
                adjn[q] = *(const int4*)(adjrow + j0n + (q >> 1) * 32 + jg * 8 + (q & 1) * 4);
                ejn[q] = *(const f4*)(ejb + j0n + (q >> 1) * 32 + jg * 8 + (q & 1) * 4);
            }
        }
#pragma unroll
        for (int sub = 0; sub < 2; ++sub) {
            const f4 ej0 = ejc[sub * 2], ej1 = ejc[sub * 2 + 1];
            const int4 a0 = adjc[sub * 2], a1 = adjc[sub * 2 + 1];
            float p[8];
            float tm = NEG_BIG;
#pragma unroll
            for (int e = 0; e < 8; ++e) {
                const float ejv = (e < 4) ? ej0[e] : ej1[e - 4];
                float sc = eival + ejv;
                sc = fmaxf(sc, ALPHA * sc);           // leaky (scale-commuted)
                const int ad = (e < 4) ? ((const int*)&a0)[e] : ((const int*)&a1)[e - 4];
                sc = ad > 0 ? sc : NEG_BIG;
                p[e] = sc;
                tm = fmaxf(tm, sc);
            }
            tm = fmaxf(tm, __shfl_xor(tm, 16));
            tm = fmaxf(tm, __shfl_xor(tm, 32));
            if (__any(tm > m + 11.5f)) {              // defer-max (8*log2e)
                const float mn = fmaxf(m, tm);
                const float fac = __builtin_amdgcn_exp2f(m - mn);
                m = mn;
                ll *= fac;
                float fr[4];
#pragma unroll
                for (int q = 0; q < 4; ++q) fr[q] = __shfl(fac, jg * 4 + q);
#pragma unroll
                for (int ft = 0; ft < 8; ++ft)
#pragma unroll
                    for (int q = 0; q < 4; ++q) acc[ft][q] *= fr[q];
            }
            float sum = 0.f;
            s16x8 afrag;
#pragma unroll
            for (int e = 0; e < 8; ++e) {
                const float pe = __builtin_amdgcn_exp2f(p[e] - m);
                afrag[e] = f2bs(pe);
                sum += pe;
            }
            sum += __shfl_xor(sum, 16);
            sum += __shfl_xor(sum, 32);
            ll += sum;
#pragma unroll
            for (int ft = 0; ft < 8; ++ft) {
                const int f = fbase + ft * 16 + li;
                const int jcr = sub * 4 + jg;
                const s16x8 bv = *(const s16x8*)((const char*)sT + cur * 32768 + f * 128 + ((jcr ^ (f & 7)) << 4));
                acc[ft] = __builtin_amdgcn_mfma_f32_16x16x32_bf16(afrag, bv, acc[ft], 0, 0, 0);
            }
        }
        if (s < 15) {
#pragma unroll
            for (int q = 0; q < 4; ++q) { adjc[q] = adjn[q]; ejc[q] = ejn[q]; }
        }
        __syncthreads();
    }

    // epilogue: normalize, ELU, store
    const float il = 1.f / ll;
    float inv[4];
#pragma unroll
    for (int q = 0; q < 4; ++q) inv[q] = __shfl(il, jg * 4 + q);
#pragma unroll
    for (int ft = 0; ft < 8; ++ft) {
#pragma unroll
        for (int q = 0; q < 4; ++q) {
            float v = acc[ft][q] * inv[q];
            v = v > 0.f ? v : __builtin_amdgcn_exp2f(v * LOG2E) - 1.f;
            out[((size_t)b * N_ + i0 + ih * 16 + jg * 4 + q) * F_ + fbase + ft * 16 + li] = v;
        }
    }
}

// ---------------------------------------------------------------------------
extern "C" void kernel_launch(void* const* d_in, const int* in_sizes, int n_in,
                              void* d_out, int out_size, void* d_ws, size_t ws_size,
                              hipStream_t stream) {
    const float* h = (const float*)d_in[0];
    const int* adj = (const int*)d_in[1];
    const float* W = (const float*)d_in[2];
    const float* a = (const float*)d_in[3];
    float* out = (float*)d_out;

    unsigned short* WhT = (unsigned short*)d_ws;          // 8 MB bf16 [b][f][m]
    float* wa = (float*)(WhT + (size_t)B_ * N_ * F_);     // 512
    float* ei = wa + 512;                                 // 16384
    float* ej = ei + (size_t)B_ * N_;                     // 16384

    k_wa<<<64, 256, 0, stream>>>(W, a, wa);
    k_gemm<<<dim3(256, 4), 256, 0, stream>>>(h, W, WhT);
    k_e2<<<(B_ * N_) / 4, 256, 0, stream>>>(h, wa, ei, ej);
    k_attn<<<512, 256, 0, stream>>>(WhT, ei, ej, adj, out);
}